// Round 6
// baseline (187.343 us; speedup 1.0000x reference)
//
#include <hip/hip_runtime.h>

// MultiHotEmbedding: out[b,s,:] = (1/max(cnt,1)) * sum_{n: x[b,s,n]!=0} emb[n,:]
// B=16,S=200,N=10000,D=64. x is EXACTLY 0/1 (bool->float), so count==sum(x)
// and the weighted sum is an unweighted sum of active emb rows.
//
// 1 block (256 thr = 4 waves) per row.
// P1: two passes; each pass issues 5 float4 loads back-to-back into registers
//     (5 loads in flight per wave -- the R5 version had ONE: load->wait->branch
//     serialization was the latency bottleneck), then scans them, compacting
//     active class indices into LDS.
// P2: waves split the active list; 2 independent accumulators for MLP.
//     LDS reduce, scale by 1/max(cnt,1), write 256 B.

#define NCLS 10000
#define DIM 64
#define NROWS (16 * 200)
#define NV4 (NCLS / 4)          // 2500 float4 per row
#define MAXA 256                // mean actives=50, sigma~7; 256 is ~29 sigma

typedef float f32x4 __attribute__((ext_vector_type(4)));

__global__ __launch_bounds__(256) void multihot_emb_kernel(
    const float* __restrict__ x,
    const float* __restrict__ emb,
    float* __restrict__ out) {

    const int row  = blockIdx.x;    // 0..3199
    const int t    = threadIdx.x;   // 0..255
    const int lane = t & 63;
    const int wave = t >> 6;

    __shared__ int   s_cls[MAXA];
    __shared__ int   s_cnt;
    __shared__ float s_acc[4][DIM];

    if (t == 0) s_cnt = 0;
    __syncthreads();

    const f32x4* __restrict__ xr =
        reinterpret_cast<const f32x4*>(x + (size_t)row * NCLS);

    // ---- phase 1: batched-load scan + index compaction ----
    #pragma unroll
    for (int half = 0; half < 2; ++half) {
        // issue 5 loads with no intervening control flow -> 5 in flight
        f32x4 v[5];
        #pragma unroll
        for (int it = 0; it < 5; ++it) {
            const int i4 = (half * 5 + it) * 256 + t;
            if (i4 < NV4) v[it] = xr[i4];
            else          v[it] = (f32x4){0.f, 0.f, 0.f, 0.f};
        }
        // consume (waitcnt counts down as each v[it] is first touched)
        #pragma unroll
        for (int it = 0; it < 5; ++it) {
            const int i4 = (half * 5 + it) * 256 + t;
            #pragma unroll
            for (int j = 0; j < 4; ++j) {
                if (v[it][j] != 0.0f) {
                    int p = atomicAdd(&s_cnt, 1);
                    if (p < MAXA) s_cls[p] = 4 * i4 + j;
                }
            }
        }
    }
    __syncthreads();

    int cnt = s_cnt;
    if (cnt > MAXA) cnt = MAXA;   // statistically unreachable

    // ---- phase 2: parallel gather, waves split the list, 2-deep MLP ----
    float acc0 = 0.0f, acc1 = 0.0f;
    int k = wave;
    for (; k + 4 < cnt; k += 8) {
        acc0 += emb[(size_t)s_cls[k]     * DIM + lane];
        acc1 += emb[(size_t)s_cls[k + 4] * DIM + lane];
    }
    if (k < cnt) acc0 += emb[(size_t)s_cls[k] * DIM + lane];

    s_acc[wave][lane] = acc0 + acc1;
    __syncthreads();

    if (wave == 0) {
        const float a = s_acc[0][lane] + s_acc[1][lane] +
                        s_acc[2][lane] + s_acc[3][lane];
        out[(size_t)row * DIM + lane] = a / fmaxf((float)cnt, 1.0f);
    }
}

extern "C" void kernel_launch(void* const* d_in, const int* in_sizes, int n_in,
                              void* d_out, int out_size, void* d_ws, size_t ws_size,
                              hipStream_t stream) {
    const float* x   = (const float*)d_in[0];   // [16,200,10000] f32
    const float* emb = (const float*)d_in[1];   // [10000,64] f32
    float* out = (float*)d_out;                 // [16,200,64] f32

    multihot_emb_kernel<<<NROWS, 256, 0, stream>>>(x, emb, out);
}